// Round 8
// baseline (258.954 us; speedup 1.0000x reference)
//
#include <hip/hip_runtime.h>
#include <stdint.h>

// GAT layer on MI355X: B=8, N=2048, F=128.
// h = x@W^T ; s1=h@a1 ; s2=h@a2 ; e=leaky(s1[i]+s2[j]); masked softmax; out=attn@h
//
// R8: adj-stream elimination. Evidence: R6 (counted vmcnt) and R7 (2x waves)
// both neutral; all staged variants 63-73us with every pipe idle -> the
// convoy waits on adj delivery (134MB/dispatch, ~half from HBM). Fix: pack
// adj to 1 bit/entry (4MB total, 512KB/batch = XCD-L2-resident like hT) in
// a gat_h tail pass; attn reads ONE uint32 per lane per 32-j chunk (L1-hot:
// one 64B line serves 16 chunks). s2 staged to LDS once. Per-iter VMEM:
// 12 -> 5 ops, all XCD-local. Structure otherwise = R7 (proven).
//
// K1 (gat_h): W fp32->bf16 swizzled LDS once/block; split-precision x(hi+lo)
//     MFMA; writes U32-swizzled 8KB-chunk hT + s1/s2; tail packs adj bits.
// K2 (gat_attn): 512 blocks x 512 thr (8 waves = 2 rh x 4 jq), TJ=32 chunks,
//     ring-2 LDS 64KB -> 2 blk/CU = 16 waves/CU.

#define B_ 8
#define N_ 2048
#define FD 128
#define ALPHA_ 0.2f
#define TJ 32
#define NCH 16                    // chunks per j-quarter (512/32)
#define CHU4 512                  // u4 per chunk: 128 o x 4 u4 (8 KB)

typedef __attribute__((ext_vector_type(8))) short short8;
typedef __attribute__((ext_vector_type(4))) float f32x4;

// 4-bit XOR swizzle for the 128x128 W tile in gat_h (16B-chunk units)
#define HCHUNK(o, jc) ((((o) * 16) + ((jc) ^ ((o) & 15))) * 8)  // ushort offset
// row-pair interleaved swizzle for 128x32 hT chunks (uint4 units)
// o in [0,128), jc in [0,4): bijective onto [0,512)  (R7-verified)
#define U32(o, jc) (((o) >> 1) * 8 + ((((((o) & 1) << 2)) | (jc)) ^ (((o) >> 1) & 7)))

__device__ __forceinline__ float bf2f(unsigned short u) {
    union { uint32_t i; float f; } v; v.i = ((uint32_t)u) << 16; return v.f;
}
__device__ __forceinline__ unsigned short f2bf(float f) {
    union { float f; uint32_t i; } v; v.f = f;
    uint32_t x = v.i;
    uint32_t r = (x + 0x7fffu + ((x >> 16) & 1u)) >> 16;  // RNE
    return (unsigned short)r;
}

// async global->LDS, 16B per lane. lds dst must be wave-uniform base;
// HW writes base + lane*16 (m104/m108). Our staging is an identity copy.
__device__ __forceinline__ void gl2lds16(const uint4* g, uint4* l) {
    __builtin_amdgcn_global_load_lds(
        (const __attribute__((address_space(1))) uint32_t*)g,
        (__attribute__((address_space(3))) uint32_t*)l, 16, 0, 0);
}

// ---------------------------------------------------------------------------
// Kernel 1: h = x@W^T via split-bf16 MFMA; writes U32-chunked hT + s1/s2;
// tail section packs adj (int32 0/1) to 1 bit/entry.
// 256 blocks x 256 threads; block = 64 rows x 128 outs; wave w: rows w*16..+16.
// C/D: col=lane&15, row=quad*4+reg  (m89/m91-verified layout).
// ---------------------------------------------------------------------------
__global__ __launch_bounds__(256) void gat_h(
    const float* __restrict__ x,
    const float* __restrict__ W,
    const float* __restrict__ a,
    const int* __restrict__ adj,
    unsigned short* __restrict__ hT,   // chunked: [b][kc32][U32(o,jc2)*8 + (j&7)]
    float* __restrict__ s1o, float* __restrict__ s2o,
    uint32_t* __restrict__ adjp)       // packed: [b][row][j/32]
{
    __shared__ __align__(16) unsigned short Wlds[FD * FD];  // 32KB, swizzled

    const int bid = blockIdx.x;
    const int tid = threadIdx.x;
    const int w = tid >> 6;
    const int lane = tid & 63;
    const int m = lane & 15;
    const int quad = lane >> 4;
    const int arow = bid * 64 + w * 16 + m;   // A-operand row for this lane

    // ---- stage W (fp32 -> bf16) into swizzled LDS, once per block ----
#pragma unroll
    for (int it = 0; it < 8; it++) {
        int cid = it * 256 + tid;          // 2048 16B-chunks
        int o = cid >> 4, kc = cid & 15;
        const float* wp = W + (size_t)o * FD + kc * 8;
        float4 w0 = *(const float4*)wp;
        float4 w1 = *(const float4*)(wp + 4);
        uint4 pk;
        pk.x = (uint32_t)f2bf(w0.x) | ((uint32_t)f2bf(w0.y) << 16);
        pk.y = (uint32_t)f2bf(w0.z) | ((uint32_t)f2bf(w0.w) << 16);
        pk.z = (uint32_t)f2bf(w1.x) | ((uint32_t)f2bf(w1.y) << 16);
        pk.w = (uint32_t)f2bf(w1.z) | ((uint32_t)f2bf(w1.w) << 16);
        *(uint4*)&Wlds[HCHUNK(o, kc)] = pk;
    }
    __syncthreads();

    f32x4 acc[8];
#pragma unroll
    for (int ot = 0; ot < 8; ot++) acc[ot] = (f32x4){0.f, 0.f, 0.f, 0.f};

#pragma unroll
    for (int ks = 0; ks < 4; ks++) {
        const float* xp = x + (size_t)arow * FD + ks * 32 + quad * 8;
        float4 x0 = *(const float4*)xp;
        float4 x1 = *(const float4*)(xp + 4);
        float xv[8] = {x0.x, x0.y, x0.z, x0.w, x1.x, x1.y, x1.z, x1.w};
        union { unsigned short us[8]; short8 v; } ahi, alo;
#pragma unroll
        for (int jj = 0; jj < 8; jj++) {
            unsigned short hi = f2bf(xv[jj]);
            ahi.us[jj] = hi;
            alo.us[jj] = f2bf(xv[jj] - bf2f(hi));
        }
#pragma unroll
        for (int ot = 0; ot < 8; ot++) {
            union { uint4 u; short8 v; } bw;
            bw.u = *(const uint4*)&Wlds[HCHUNK(ot * 16 + m, ks * 4 + quad)];
            acc[ot] = __builtin_amdgcn_mfma_f32_16x16x32_bf16(ahi.v, bw.v, acc[ot], 0, 0, 0);
            acc[ot] = __builtin_amdgcn_mfma_f32_16x16x32_bf16(alo.v, bw.v, acc[ot], 0, 0, 0);
        }
    }

    // Epilogue: store hT (U32-chunked, bf16) + s1/s2 partial reduce.
    const int rc0 = bid * 64 + w * 16 + quad * 4;  // C rows rc0..rc0+3 (= j)
    const int bb = rc0 >> 11;                      // batch
    const int jb = rc0 & (N_ - 1);
    const int kc = jb >> 5;                        // 32-j chunk
    const int jc2 = (jb & 31) >> 3;                // u4 j-slot in chunk
    const int off = jb & 7;                        // 0 or 4
    unsigned short* hTb = hT + (size_t)bb * FD * N_ + (size_t)kc * (CHU4 * 8);
    float s1p[4] = {0.f, 0.f, 0.f, 0.f};
    float s2p[4] = {0.f, 0.f, 0.f, 0.f};
#pragma unroll
    for (int ot = 0; ot < 8; ot++) {
        const int o = ot * 16 + m;
        uint2 pk;
        pk.x = (uint32_t)f2bf(acc[ot][0]) | ((uint32_t)f2bf(acc[ot][1]) << 16);
        pk.y = (uint32_t)f2bf(acc[ot][2]) | ((uint32_t)f2bf(acc[ot][3]) << 16);
        *(uint2*)(hTb + (size_t)U32(o, jc2) * 8 + off) = pk;
        float a1v = a[o], a2v = a[FD + o];
#pragma unroll
        for (int r = 0; r < 4; r++) {
            s1p[r] += acc[ot][r] * a1v;
            s2p[r] += acc[ot][r] * a2v;
        }
    }
#pragma unroll
    for (int offx = 8; offx >= 1; offx >>= 1) {
#pragma unroll
        for (int r = 0; r < 4; r++) {
            s1p[r] += __shfl_xor(s1p[r], offx);
            s2p[r] += __shfl_xor(s2p[r], offx);
        }
    }
    if (m == 0) {
#pragma unroll
        for (int r = 0; r < 4; r++) {
            s1o[rc0 + r] = s1p[r];
            s2o[rc0 + r] = s2p[r];
        }
    }

    // ---- tail: pack adj to bits. 1,048,576 words; 65536 threads x 16. ----
    // word widx covers adj ints [widx*32, +32); bit (q*4+c) = (int > 0).
    const int tall = bid * 256 + tid;
#pragma unroll 1
    for (int it = 0; it < 16; it++) {
        const int widx = it * 65536 + tall;
        uint32_t bits = 0;
#pragma unroll
        for (int q = 0; q < 8; q++) {
            int4 v = ((const int4*)adj)[(size_t)widx * 8 + q];
            bits |= (v.x > 0 ? 1u : 0u) << (q * 4 + 0);
            bits |= (v.y > 0 ? 1u : 0u) << (q * 4 + 1);
            bits |= (v.z > 0 ? 1u : 0u) << (q * 4 + 2);
            bits |= (v.w > 0 ? 1u : 0u) << (q * 4 + 3);
        }
        adjp[widx] = bits;
    }
}

// ---------------------------------------------------------------------------
// Kernel 2: fused masked-softmax + PV (MFMA), bit-mask adj, 16 waves/CU.
// 512 blocks (b=bid&7 XCD-pin, i0=(bid>>3)*32) x 512 thr (8 waves).
// Wave w: rh=w&1 (rows [i0+rh*16,+16)), jq=w>>1 (j in [jq*512,+512)).
// Per jq: 16 chunks of 32 j, ring-2 LDS (8KB each), staged via gl2lds.
// adj mask: 1 uint32/lane/chunk from L2-resident packed buffer (prefetched).
// s2 staged to LDS once. LDS 72.5KB -> 2 blocks/CU = 16 waves/CU.
// Epilogue: jq>0 push acc/rowsum via LDS; jq=0 combines, divides, writes.
// ---------------------------------------------------------------------------
__global__ __launch_bounds__(512, 4) void gat_attn(
    const uint32_t* __restrict__ adjp,
    const unsigned short* __restrict__ hT,
    const float* __restrict__ s1,
    const float* __restrict__ s2,
    float* __restrict__ out)
{
    __shared__ __align__(16) uint4 hbuf[4][2][CHU4];  // [jq][buf], 64 KB
    __shared__ float s2lds[N_];                       // 8 KB (this batch's row)
    __shared__ float rsq[4][2][16];                   // per-(jq,rh) rowsums

    const int bid = blockIdx.x;
    const int b = bid & 7;              // batch -> XCD pin
    const int ib = bid >> 3;            // 0..63
    const int i0 = ib * 32;
    const int tid = threadIdx.x;
    const int lane = tid & 63;
    const int w = tid >> 6;             // 0..7
    const int rh = w & 1;               // row-group
    const int jq = w >> 1;              // j-quarter 0..3
    const int m = lane & 15;
    const int quad = lane >> 4;

    const int irow = i0 + rh * 16 + m;     // this lane's P row (A-frag m)
    const float s1v = s1[b * N_ + irow];
    // packed-mask row for this lane's row, this jq: 16 consecutive words
    const uint32_t* pwrow = adjp + ((size_t)(b * N_ + irow)) * (N_ / 32) + jq * NCH;
    const uint4* hTq = (const uint4*)hT + (size_t)b * (FD * N_ / 8)
                       + (size_t)jq * NCH * CHU4;

    // ---- prologue: stage s2 row + chunk 0; prefetch mask word 0 ----
    *(float4*)&s2lds[tid * 4] = *(const float4*)(s2 + b * N_ + tid * 4);
#pragma unroll
    for (int q = 0; q < 4; q++)
        gl2lds16(&hTq[rh * 256 + q * 64 + lane], &hbuf[jq][0][rh * 256 + q * 64]);
    uint32_t pw = pwrow[0];
    __syncthreads();

    f32x4 acc[8];
#pragma unroll
    for (int ot = 0; ot < 8; ot++) acc[ot] = (f32x4){0.f, 0.f, 0.f, 0.f};
    float rs_loc = 0.f;

    for (int k = 0; k < NCH; k++) {
        const int buf = k & 1;
        const bool more = (k + 1 < NCH);
        uint32_t npw = 0;
        if (more) {
            // stage chunk k+1 (in flight across compute; barrier drains)
#pragma unroll
            for (int q = 0; q < 4; q++)
                gl2lds16(&hTq[(size_t)(k + 1) * CHU4 + rh * 256 + q * 64 + lane],
                         &hbuf[jq][buf ^ 1][rh * 256 + q * 64]);
            npw = pwrow[k + 1];
        }

        // ---- compute chunk k: softmax on 8 j/lane + 8 MFMA (K=32) ----
        {
            const float* sp = &s2lds[jq * 512 + k * TJ + quad * 8];
            float4 sc0 = *(const float4*)sp;
            float4 sc1 = *(const float4*)(sp + 4);
            float sarr[8] = {sc0.x, sc0.y, sc0.z, sc0.w, sc1.x, sc1.y, sc1.z, sc1.w};
            const uint32_t bits = pw >> (quad * 8);
            union { unsigned short us[8]; short8 v; } af;
#pragma unroll
            for (int jj = 0; jj < 8; jj++) {
                float e = s1v + sarr[jj];
                e = (e > 0.f) ? e : (ALPHA_ * e);
                float p = ((bits >> jj) & 1u) ? __expf(e) : 0.f;
                rs_loc += p;
                af.us[jj] = f2bf(p);
            }
#pragma unroll
            for (int ot = 0; ot < 8; ot++) {
                const int o = ot * 16 + m;  // B-frag n = lane&15
                union { uint4 u; short8 v; } bf;
                bf.u = *(const uint4*)&hbuf[jq][buf][U32(o, quad)];
                acc[ot] = __builtin_amdgcn_mfma_f32_16x16x32_bf16(af.v, bf.v, acc[ot], 0, 0, 0);
            }
        }

        __syncthreads();  // drains vmcnt: chunk k+1 staged; safe to flip
        if (more) pw = npw;
    }

    // ---- rowsum: lanes m, m+16, m+32, m+48 hold partials of row m ----
    rs_loc += __shfl_xor(rs_loc, 16);
    rs_loc += __shfl_xor(rs_loc, 32);

    // ---- cross-jq combine via LDS (xch overlays hbuf; barrier above done) ----
    float* xch = (float*)&hbuf[0][0][0];   // [3][32][132] floats = 50.7 KB
    if (jq != 0) {
#pragma unroll
        for (int ot = 0; ot < 8; ot++)
#pragma unroll
            for (int r = 0; r < 4; r++)
                xch[((jq - 1) * 32 + rh * 16 + quad * 4 + r) * 132 + ot * 16 + m]
                    = acc[ot][r];
        if (quad == 0) rsq[jq][rh][m] = rs_loc;
    }
    __syncthreads();
    if (jq == 0) {
        float rinv[4];
#pragma unroll
        for (int r = 0; r < 4; r++) {
            const int p = quad * 4 + r;
            float rtot = __shfl(rs_loc, p)
                       + rsq[1][rh][p] + rsq[2][rh][p] + rsq[3][rh][p];
            rinv[r] = 1.0f / rtot;
        }
        float* outp = out + (size_t)(b * N_ + i0 + rh * 16) * FD;
#pragma unroll
        for (int ot = 0; ot < 8; ot++) {
            const int col = ot * 16 + m;
#pragma unroll
            for (int r = 0; r < 4; r++) {
                const int row = rh * 16 + quad * 4 + r;
                float v = acc[ot][r]
                        + xch[(row) * 132 + col]
                        + xch[(32 + row) * 132 + col]
                        + xch[(64 + row) * 132 + col];
                outp[(size_t)(quad * 4 + r) * FD + col] = v * rinv[r];
            }
        }
    }
}

// ---------------------------------------------------------------------------
extern "C" void kernel_launch(void* const* d_in, const int* in_sizes, int n_in,
                              void* d_out, int out_size, void* d_ws, size_t ws_size,
                              hipStream_t stream) {
    const void* xv = d_in[0];
    const void* adjv = d_in[1];
    const void* Wv = d_in[2];
    const void* av = d_in[3];
    for (int i = 0; i < n_in; i++) {
        switch (in_sizes[i]) {
            case 2097152:  xv = d_in[i]; break;
            case 33554432: adjv = d_in[i]; break;
            case 16384:    Wv = d_in[i]; break;
            case 256:      av = d_in[i]; break;
            default: break;
        }
    }
    const float* x = (const float*)xv;
    const int* adj = (const int*)adjv;
    const float* W = (const float*)Wv;
    const float* a = (const float*)av;
    float* out = (float*)d_out;

    // ws: hT 4MB | s1 64KB | s2 64KB | adjp 4MB
    char* p = (char*)d_ws;
    unsigned short* hT = (unsigned short*)p;  p += (size_t)B_ * FD * N_ * 2;
    float* s1 = (float*)p;                    p += (size_t)B_ * N_ * 4;
    float* s2 = (float*)p;                    p += (size_t)B_ * N_ * 4;
    uint32_t* adjp = (uint32_t*)p;

    gat_h<<<256, 256, 0, stream>>>(x, W, a, adj, hT, s1, s2, adjp);
    gat_attn<<<512, 512, 0, stream>>>(adjp, hT, s1, s2, out);
}